// Round 1
// 327.672 us; speedup vs baseline: 1.0116x; 1.0116x over previous
//
#include <hip/hip_runtime.h>

#define B 64
#define H 56
#define W 56
#define C 256
#define ROUTES 4
#define CONV_OUT 64
#define BN_EPS 0.001f
#define RW (C / ROUTES)            // 64 channels per route
#define X_SIZE ((long)B * H * W * RW)

// ws layout (floats):
//   P2[B][H][3][C]  per-row partials: {even-w sum, odd-w sum, col-0 value}
//                   written NON-atomically by k_reduce (no memset needed)
//   U[10][C][4]     folded (conv_w x fc_w x BN x counts) routing tensor
//   route[B] (int)
#define P2_FLOATS ((long)B * H * 3 * C)     // 2,752,512 (~11 MB)
#define OFFU P2_FLOATS
#define U_FLOATS (10L * C * 4)              // 10,240
#define OFFROUTE (OFFU + U_FLOATS)

typedef float floatx4 __attribute__((ext_vector_type(4)));

__device__ __forceinline__ void f4add(float4& a, const float4& v) {
    a.x += v.x; a.y += v.y; a.z += v.z; a.w += v.w;
}

// ---------------------------------------------------------------------------
// Kernel 1 (grid = B*H + 4):
//  blocks [0, B*H): per-row parity sums -> PLAIN float4 stores into
//    P2[b][h][q][C], q: 0 = even-w sum, 1 = odd-w sum, 2 = col-0 value.
//    (replaces the previous 2.8M cross-XCD atomicAdds)
//  blocks [B*H, B*H+4): fold conv_w (read ONCE total) + fc_w + BN + tap counts
//    into U[10][C][4]:  routing[b][r] = sum_c( sum_j P[b][j][c]*U[j][c][r]
//                                              + U[9][c][r] ) + const[r]
// ---------------------------------------------------------------------------
__global__ __launch_bounds__(256) void k_reduce(const float* __restrict__ x,
                                                const float* __restrict__ gamma,
                                                const float* __restrict__ beta,
                                                const float* __restrict__ mmean,
                                                const float* __restrict__ mvar,
                                                const float* __restrict__ conv_w,
                                                const float* __restrict__ fc_w,
                                                float* __restrict__ ws) {
    int tid = threadIdx.x;

    if (blockIdx.x >= B * H) {
        // ---- fold branch: 4 blocks x 256 threads; thread = (c within 64, r)
        __shared__ float fcw_s[CONV_OUT * ROUTES];     // fc_w[o][r]
        fcw_s[tid] = fc_w[tid];                        // 256 == 64*4
        __syncthreads();

        int c = (blockIdx.x - B * H) * 64 + (tid >> 2);
        int r = tid & 3;

        float t[9];
        #pragma unroll
        for (int k = 0; k < 9; ++k) {
            const float4* w4 = (const float4*)conv_w + ((long)(k * C + c) * CONV_OUT) / 4;
            float s = 0.f;
            #pragma unroll
            for (int o4 = 0; o4 < 16; ++o4) {
                float4 wv = w4[o4];
                s += wv.x * fcw_s[(o4 * 4 + 0) * 4 + r];
                s += wv.y * fcw_s[(o4 * 4 + 1) * 4 + r];
                s += wv.z * fcw_s[(o4 * 4 + 2) * 4 + r];
                s += wv.w * fcw_s[(o4 * 4 + 3) * 4 + r];
            }
            t[k] = s;                                 // t[k] = sum_o w[k][c][o] fc_w[o][r]
        }

        float a  = gamma[c] * rsqrtf(mvar[c] + BN_EPS);
        float bb = beta[c] - mmean[c] * a;

        // Sx[k] in terms of P[j]:  Sx = {P0, P1, P0-P4, P2, P3, P2-P5,
        //                                P0-P6, P1-P7, P0-P6-P4+P8}
        float u[10];
        u[0] =  t[0] + t[2] + t[6] + t[8];
        u[1] =  t[1] + t[7];
        u[2] =  t[3] + t[5];
        u[3] =  t[4];
        u[4] = -(t[2] + t[8]);
        u[5] = -t[5];
        u[6] = -(t[6] + t[8]);
        u[7] = -t[7];
        u[8] =  t[8];
        // sum_k cnt[k]*t[k], cnt = {784,784,756,784,784,756,756,756,729}
        u[9] = 784.f * (t[0] + t[1] + t[3] + t[4])
             + 756.f * (t[2] + t[5] + t[6] + t[7])
             + 729.f * t[8];

        float* U = ws + OFFU;
        float sa = a * (1.f / 784.f);
        #pragma unroll
        for (int j = 0; j < 9; ++j) U[(j * C + c) * 4 + r] = sa * u[j];
        U[(9 * C + c) * 4 + r] = bb * (1.f / 784.f) * u[9];
        return;
    }

    // ---- row-reduce branch: one (b,h) row per block
    int blk = blockIdx.x;               // b*H + h
    int cg = tid & 63;
    int wg = tid >> 6;                  // 0..3 -> w = wg, wg+4, ...

    const float4* xv = (const float4*)x;
    long base = (long)blk * W * (C / 4) + cg;

    float4 v[14];
    #pragma unroll
    for (int i = 0; i < 14; ++i) v[i] = xv[base + (long)(wg + 4 * i) * (C / 4)];

    float4 a4 = {0,0,0,0}, b4 = {0,0,0,0};
    #pragma unroll
    for (int i = 0; i < 14; i += 2) { f4add(a4, v[i]); f4add(b4, v[i + 1]); }
    f4add(a4, b4);                      // sum over w === wg (mod 4)

    __shared__ float4 lds[4][64];
    lds[wg][cg] = a4;
    __syncthreads();

    float4* P2 = (float4*)ws + (long)blk * 3 * 64;   // [3][64] float4 per row
    if (wg == 0) {                       // even-w sum (wg 0 & 2)
        float4 e = lds[0][cg]; f4add(e, lds[2][cg]);
        P2[cg]       = e;                // q=0: even-w row sum
        P2[128 + cg] = v[0];             // q=2: col-0 value (w==0)
    } else if (wg == 1) {                // odd-w sum (wg 1 & 3)
        float4 o = lds[1][cg]; f4add(o, lds[3][cg]);
        P2[64 + cg]  = o;                // q=1: odd-w row sum
    }
}

// ---------------------------------------------------------------------------
// Kernel 2: per-batch routing. 64 blocks x 256 threads. Each thread first
// reduces its channel's 56 row-partials (168 coalesced loads, 11 MB total
// grid-wide) into the 9 grid-sum primitives, then folds with U.
// ---------------------------------------------------------------------------
__global__ __launch_bounds__(256) void k_route(const float* __restrict__ ws,
                                               const float* __restrict__ conv_b,
                                               const float* __restrict__ fc_w,
                                               const float* __restrict__ fc_b,
                                               float* __restrict__ out_routing,
                                               int* __restrict__ route) {
    __shared__ floatx4 red[256];
    __shared__ float rxs[ROUTES];

    int b = blockIdx.x;
    int c = threadIdx.x;
    const float* Pb = ws + (long)b * H * 3 * C;

    // h-parity reduction over the 56 per-row partials (H even: 28 pairs)
    float See = 0.f, Seo = 0.f, c0e = 0.f;
    float Soe = 0.f, Soo = 0.f, c0o = 0.f;
    #pragma unroll 4
    for (int h = 0; h < H; h += 2) {
        const float* re = Pb + (long)h * 3 * C + c;   // even row
        See += re[0];
        Seo += re[C];
        c0e += re[2 * C];
        Soe += re[3 * C];                             // odd row (h+1)
        Soo += re[4 * C];
        c0o += re[5 * C];
    }
    float r0e = Pb[c];                                // row-0 extras (L2 hits)
    float r0o = Pb[C + c];
    float x00 = Pb[2 * C + c];

    float Pj[9] = {See, Seo, Soe, Soo, c0e, c0o, r0e, r0o, x00};

    const floatx4* U4 = (const floatx4*)(ws + OFFU);
    floatx4 v = U4[9 * C + c];                        // bias-fold term
    #pragma unroll
    for (int j = 0; j < 9; ++j) v += Pj[j] * U4[j * C + c];

    red[c] = v;
    __syncthreads();
    #pragma unroll
    for (int s = 128; s >= 1; s >>= 1) {
        if (c < s) red[c] += red[c + s];
        __syncthreads();
    }

    if (c < ROUTES) {
        float cst = fc_b[c];
        for (int o = 0; o < CONV_OUT; ++o) cst += conv_b[o] * fc_w[o * ROUTES + c];
        float val = red[0][c] + cst;
        rxs[c] = val;
        out_routing[b * ROUTES + c] = val;
    }
    __syncthreads();
    if (c == 0) {
        int best = 0;                              // jnp.argmax: first max wins
        for (int r = 1; r < ROUTES; ++r) if (rxs[r] > rxs[best]) best = r;
        route[b] = best;
    }
}

// ---------------------------------------------------------------------------
// Kernel 3: gather. 3136 blocks x 256 threads x 4 independent float4 each
// (ILP for latency hiding); b is block-uniform (49 blocks per batch).
// Nontemporal store: output never re-read, keep input L3-resident.
// ---------------------------------------------------------------------------
__global__ __launch_bounds__(256) void k_gather(const float* __restrict__ x,
                                                const int* __restrict__ route,
                                                float* __restrict__ out) {
    long base4 = (long)blockIdx.x * 1024 + threadIdx.x;
    int b = blockIdx.x / 49;                       // 3136/64 pixels, 64 px/block
    int rt = route[b];
    const floatx4* xv = (const floatx4*)x;
    #pragma unroll
    for (int m = 0; m < 4; ++m) {
        long idx = base4 + m * 256;
        int j = (int)(idx & 15);                   // 16 float4 per pixel
        long pixel = idx >> 4;
        floatx4 v = xv[pixel * (C / 4) + (long)rt * (RW / 4) + j];
        __builtin_nontemporal_store(v, &((floatx4*)out)[idx]);
    }
}

extern "C" void kernel_launch(void* const* d_in, const int* in_sizes, int n_in,
                              void* d_out, int out_size, void* d_ws, size_t ws_size,
                              hipStream_t stream) {
    const float* inputs = (const float*)d_in[0];
    const float* gamma  = (const float*)d_in[1];
    const float* beta   = (const float*)d_in[2];
    const float* mmean  = (const float*)d_in[3];
    const float* mvar   = (const float*)d_in[4];
    const float* conv_w = (const float*)d_in[5];
    const float* conv_b = (const float*)d_in[6];
    const float* fc_w   = (const float*)d_in[7];
    const float* fc_b   = (const float*)d_in[8];

    float* out   = (float*)d_out;
    float* ws    = (float*)d_ws;
    int*   route = (int*)((char*)d_ws + OFFROUTE * sizeof(float));

    // No memset: every word of P2/U/route is fully overwritten each launch.
    k_reduce<<<B * H + 4, 256, 0, stream>>>(inputs, gamma, beta, mmean, mvar,
                                            conv_w, fc_w, ws);
    k_route<<<B, 256, 0, stream>>>(ws, conv_b, fc_w, fc_b, out + X_SIZE, route);
    k_gather<<<3136, 256, 0, stream>>>(inputs, route, out);
}